// Round 8
// baseline (213.664 us; speedup 1.0000x reference)
//
#include <hip/hip_runtime.h>
#include <hip/hip_cooperative_groups.h>

namespace cg = cooperative_groups;

#define BB 4
#define HH 384
#define WW 384
#define HWSZ (HH * WW)
#define KK 64
#define TSH 32
#define TSW 64
#define TPB_X 6                  // tiles across (384/64)
#define TPB_Y 12                 // tiles down  (384/32)
#define NT (TPB_X * TPB_Y)       // 72 tiles per batch
#define NBLK (BB * NT)           // 288 blocks
#define MAXR 1024
#define NS 8                     // root-cache slots per accum tile
#define CANDC 2048
#define INFI 0x7FFFFFFF
#define INFV 0x7F7F7F7F
#define DTOT (BB * KK * (WW + HH))   // dcol+drow ints = 196608
#define DCHUNK 683                   // ceil(DTOT / NBLK)

// agent-scope (L1-bypass) load: needed when reading data CAS/atomically
// written by other blocks within this same kernel
__device__ __forceinline__ int aload(const int* p) {
    return __hip_atomic_load(p, __ATOMIC_RELAXED, __HIP_MEMORY_SCOPE_AGENT);
}

__device__ __forceinline__ int afind(int* par, int i) {
    while (true) {
        int p = aload(&par[i]);
        if (p == i) return i;
        i = p;
    }
}

__device__ __forceinline__ void auni(int* par, int a, int b) {
    while (true) {
        a = afind(par, a);
        b = afind(par, b);
        if (a == b) return;
        if (a > b) { int t = a; a = b; b = t; }
        int old = atomicCAS(&par[b], b, a);
        if (old == b) return;
        b = old;
    }
}

// ---- union-find on LDS
__device__ __forceinline__ int lfind(int* par, int i) {
    while (true) {
        int p = par[i];
        if (p == i) return i;
        int gp = par[p];
        if (gp == p) return p;
        par[i] = gp;
        i = gp;
    }
}

__device__ __forceinline__ void luni(int* par, int a, int b) {
    while (true) {
        a = lfind(par, a);
        b = lfind(par, b);
        if (a == b) return;
        if (a > b) { int t = a; a = b; b = t; }
        int old = atomicCAS(&par[b], b, a);
        if (old == b) return;
        b = old;
    }
}

__device__ __forceinline__ int lookup_k(const int* sids, int r) {
    int lo = 0, hi = KK - 1;
    while (lo <= hi) {
        int mid = (lo + hi) >> 1;
        int v = sids[mid];
        if (v == r) return mid;
        if (v < r) lo = mid + 1; else hi = mid - 1;
    }
    return -1;
}

union SMem {
    struct {                                     // phase A: tile CC
        int lp[TSH * TSW];                       // 8 KB
        unsigned short leadL[MAXR];              // 2 KB
        unsigned short rootL[MAXR];              // 2 KB
        int nLead, nRoot;
    } a;
    struct {                                     // phase C: select
        int pf[NT + 1];
        int cand[CANDC];                         // 8 KB
        int cnt;
    } c;
    struct {                                     // phase D: accum
        int sids[KK];
        unsigned long long table[NS];
        int scol[NS][TSW];
        int srow[NS][TSH];
    } d;
    struct {                                     // phase E: bbox
        int s[4][4];
    } e;
};

__global__ __launch_bounds__(256) void fused_k(const float* __restrict__ x,
                                               int* __restrict__ parent,
                                               int* __restrict__ tileCnt,
                                               int* __restrict__ tileList,
                                               int* __restrict__ ids,
                                               int* __restrict__ dcol,
                                               int* __restrict__ drow,
                                               int* __restrict__ out) {
    cg::grid_group grid = cg::this_grid();
    __shared__ SMem sm;
    int blk = blockIdx.x, tid = threadIdx.x;
    int ln = tid & 63, wv = tid >> 6;

    // ================= Phase A: per-tile CC + dcol/drow init =================
    {
        int b = blk / NT, t2 = blk - b * NT;
        int th0 = (t2 / TPB_X) * TSH, tw0 = (t2 % TPB_X) * TSW;
        int* par = parent + b * HWSZ;

        int beg = blk * DCHUNK;
        int end = beg + DCHUNK; if (end > DTOT) end = DTOT;
        for (int i = beg + tid; i < end; i += 256) dcol[i] = INFV;

        if (tid == 0) { sm.a.nLead = 0; sm.a.nRoot = 0; }
        __syncthreads();

        // pass 1: per-row horizontal run-leaders via ballot
        for (int r = wv; r < TSH; r += 4) {
            int h = th0 + r, w = tw0 + ln;
            int gi = (b * HH + h) * WW + w;
            float2 v = *(const float2*)(x + 2 * gi);
            bool m = (v.x > 0.4f) || (v.y > 0.4f);
            unsigned long long mb = __ballot(m);
            unsigned long long below = (~mb) & ((1ull << ln) - 1ull);
            int s = below ? (64 - __clzll(below)) : 0;
            int l = r * 64 + ln;
            sm.a.lp[l] = m ? (r * 64 + s) : -1;
            if (m && s == ln) {
                int i2 = atomicAdd(&sm.a.nLead, 1);
                sm.a.leadL[i2] = (unsigned short)l;
            }
        }
        __syncthreads();
        // pass 2: vertical unions, one per overlap-run (dedup via ballot)
        for (int r = wv; r < TSH; r += 4) {
            if (r == 0) continue;                // wave-uniform
            int l = r * 64 + ln;
            bool ov = (sm.a.lp[l] >= 0) && (sm.a.lp[l - 64] >= 0);
            unsigned long long ob = __ballot(ov);
            if (ov && (ln == 0 || !((ob >> (ln - 1)) & 1ull)))
                luni(sm.a.lp, l, l - 64);
        }
        __syncthreads();
        // pass 2.5: flatten leaders exactly; collect roots
        int nl = sm.a.nLead;
        for (int i = tid; i < nl; i += 256) {
            int l = sm.a.leadL[i];
            int r = lfind(sm.a.lp, l);
            if (r != l) sm.a.lp[l] = r;          // monotone, race-benign
            else { int j = atomicAdd(&sm.a.nRoot, 1); sm.a.rootL[j] = (unsigned short)l; }
        }
        __syncthreads();
        // pass 3: loop-free root per pixel; write global parent + root list
        for (int l = tid; l < TSH * TSW; l += 256) {
            int v = sm.a.lp[l];
            int h = th0 + (l >> 6), w = tw0 + (l & 63);
            int res = -1;
            if (v >= 0) {
                int r = sm.a.lp[v];
                res = (th0 + (r >> 6)) * WW + (tw0 + (r & 63));
            }
            par[h * WW + w] = res;
        }
        int nr = sm.a.nRoot;
        for (int i = tid; i < nr; i += 256) {
            int l = sm.a.rootL[i];
            tileList[blk * MAXR + i] = (th0 + (l >> 6)) * WW + (tw0 + (l & 63));
        }
        if (tid == 0) tileCnt[blk] = nr;
    }
    grid.sync();

    // ================= Phase B: cross-tile bridge (1 edge/thread) ============
    {
        const int NEV = 5 * WW;                  // vertical boundaries
        const int NE = NEV + 11 * WW;            // + horizontal = 6144 per batch
        int gid = blk * 256 + tid;
        if (gid < BB * NE) {
            int b = gid / NE, e = gid - b * NE;
            int* par = parent + b * HWSZ;
            int p, q;
            if (e < NEV) {
                int line = e / WW, pos = e - line * WW;
                p = pos * WW + (63 + 64 * line); q = p + 1;
            } else {
                int eh = e - NEV;
                int line = eh / WW, pos = eh - line * WW;
                p = (31 + 32 * line) * WW + pos; q = p + WW;
            }
            if (par[p] >= 0 && par[q] >= 0) auni(par, p, q);  // sign stable
        }
    }
    grid.sync();

    // ================= Phase C: select KK smallest roots (blocks 0..BB-1) ====
    if (blk < BB) {
        int b = blk;
        int* par = parent + b * HWSZ;
        if (tid < NT) sm.c.pf[tid + 1] = tileCnt[b * NT + tid];
        if (tid == 0) { sm.c.pf[0] = 0; sm.c.cnt = 0; }
        if (tid < KK) ids[b * KK + tid] = INFI;
        __syncthreads();
        if (tid == 0) for (int i = 0; i < NT; ++i) sm.c.pf[i + 1] += sm.c.pf[i];
        __syncthreads();
        int total = sm.c.pf[NT];
        for (int j = tid; j < total; j += 256) {
            int lo = 0, hi = NT;
            while (lo + 1 < hi) { int mid = (lo + hi) >> 1; if (sm.c.pf[mid] <= j) lo = mid; else hi = mid; }
            int v = tileList[(b * NT + lo) * MAXR + (j - sm.c.pf[lo])];
            if (aload(&par[v]) == v) {           // L1-bypass: bridged by other CUs
                int pos = atomicAdd(&sm.c.cnt, 1);
                if (pos < CANDC) sm.c.cand[pos] = v;
            }
        }
        __syncthreads();
        int m2 = sm.c.cnt < CANDC ? sm.c.cnt : CANDC;
        for (int i = tid; i < m2; i += 256) {
            int v = sm.c.cand[i];
            int r = 0;
            for (int j = 0; j < m2; ++j) r += (sm.c.cand[j] < v);
            if (r < KK) ids[b * KK + r] = v;
        }
    }
    grid.sync();

    // ================= Phase D: accum dilated col/row mins ====================
    {
        int b = blk / NT, t2 = blk - b * NT;
        int th0 = (t2 / TPB_X) * TSH, tw0 = (t2 % TPB_X) * TSW;
        int* par = parent + b * HWSZ;

        if (tid < KK) sm.d.sids[tid] = ids[b * KK + tid];
        if (tid < NS) sm.d.table[tid] = 0ull;
        for (int i = tid; i < NS * TSW; i += 256) ((int*)sm.d.scol)[i] = INFI;
        for (int i = tid; i < NS * TSH; i += 256) ((int*)sm.d.srow)[i] = INFI;
        __syncthreads();

        int lastpv = -2, lastk = -1, lastslot = -1;
        for (int c = 0; c < 2; ++c) {
            int base = (tid + c * 256) * 4;      // 0..2044
            int lh = base >> 6, lw = base & 63;
            int h = th0 + lh, w0 = tw0 + lw;
            int4 pr = *(const int4*)&par[h * WW + w0];  // stale-safe: see chase
            int fh = (h >= 2) ? h - 2 : h;
            #pragma unroll
            for (int e = 0; e < 4; ++e) {
                int pv = (e == 0) ? pr.x : (e == 1) ? pr.y : (e == 2) ? pr.z : pr.w;
                if (pv < 0) continue;
                int k, slot;
                if (pv == lastpv) { k = lastk; slot = lastslot; }
                else {
                    int r = pv, nx;
                    while ((nx = aload(&par[r])) != r) r = nx;  // post-bridge chase
                    k = -2; slot = -1;
                    for (int i2 = 0; i2 < NS; ++i2) {
                        unsigned long long ev = sm.d.table[i2];
                        if (ev == 0ull) {
                            if (k == -2) k = lookup_k(sm.d.sids, r);
                            unsigned long long me =
                                ((unsigned long long)(unsigned)(r + 1) << 32) | (unsigned)(k + 2);
                            unsigned long long old = atomicCAS(&sm.d.table[i2], 0ull, me);
                            if (old == 0ull) { slot = i2; break; }
                            ev = old;
                        }
                        if ((unsigned)(ev >> 32) == (unsigned)(r + 1)) {
                            k = (int)(unsigned)(ev & 0xffffffffull) - 2;
                            slot = i2; break;
                        }
                    }
                    if (slot < 0 && k == -2) k = lookup_k(sm.d.sids, r);
                    lastpv = pv; lastk = k; lastslot = slot;
                }
                if (k < 0) continue;
                int w = w0 + e;
                int fw = (w >= 2) ? w - 2 : w;
                if (slot >= 0) {
                    atomicMin(&sm.d.scol[slot][lw + e], fh);
                    atomicMin(&sm.d.srow[slot][lh], fw);
                } else {
                    atomicMin(&dcol[(b * KK + k) * WW + w], fh);
                    atomicMin(&drow[(b * KK + k) * HH + h], fw);
                }
            }
        }
        __syncthreads();
        for (int i = tid; i < NS * TSW; i += 256) {
            int s = i >> 6, pos = i & 63;
            unsigned long long ev = sm.d.table[s];
            if (ev == 0ull) continue;
            int k = (int)(unsigned)(ev & 0xffffffffull) - 2;
            if (k < 0) continue;
            int v = sm.d.scol[s][pos];
            if (v < INFI) atomicMin(&dcol[(b * KK + k) * WW + tw0 + pos], v);
            if (pos < TSH) {
                int v2 = sm.d.srow[s][pos];
                if (v2 < INFI) atomicMin(&drow[(b * KK + k) * HH + th0 + pos], v2);
            }
        }
    }
    grid.sync();

    // ================= Phase E: bbox (blocks 0..BB*KK-1) ======================
    if (blk < BB * KK) {
        const int* dc = dcol + blk * WW;
        const int* dr = drow + blk * HH;
        int cmin = INFI, cmax = -1, rmin = INFI, rmax = -1;
        #pragma unroll
        for (int pi = 0; pi < 2; ++pi) {
            int p = tid + pi * 256;
            if (p < WW) {
                int hm = aload(&dc[p]);          // L1-bypass: atomicMin'd by others
                if (p >= 2) hm = min(hm, aload(&dc[p - 2]));
                if (p + 2 < WW) hm = min(hm, aload(&dc[p + 2]));
                if (hm < INFV && hm >= 1) { cmin = min(cmin, p); cmax = max(cmax, p); }
                int wm = aload(&dr[p]);
                if (p >= 2) wm = min(wm, aload(&dr[p - 2]));
                if (p + 2 < HH) wm = min(wm, aload(&dr[p + 2]));
                if (wm < INFV && wm >= 1) { rmin = min(rmin, p); rmax = max(rmax, p); }
            }
        }
        for (int o = 1; o < 64; o <<= 1) {
            cmin = min(cmin, __shfl_xor(cmin, o));
            cmax = max(cmax, __shfl_xor(cmax, o));
            rmin = min(rmin, __shfl_xor(rmin, o));
            rmax = max(rmax, __shfl_xor(rmax, o));
        }
        if (ln == 0) { sm.e.s[0][wv] = cmin; sm.e.s[1][wv] = cmax;
                       sm.e.s[2][wv] = rmin; sm.e.s[3][wv] = rmax; }
        __syncthreads();
        if (tid == 0) {
            int CMin = sm.e.s[0][0], CMax = sm.e.s[1][0];
            int RMin = sm.e.s[2][0], RMax = sm.e.s[3][0];
            for (int i = 1; i < 4; ++i) {
                CMin = min(CMin, sm.e.s[0][i]); CMax = max(CMax, sm.e.s[1][i]);
                RMin = min(RMin, sm.e.s[2][i]); RMax = max(RMax, sm.e.s[3][i]);
            }
            int x2, y2, wext, hext;
            if (RMax >= 0) { x2 = RMin; wext = RMax - RMin; } else { x2 = 0; wext = 1; }
            if (CMax >= 0) { y2 = CMin; hext = CMax - CMin; } else { y2 = 0; hext = 1; }
            out[blk * 4 + 0] = x2;
            out[blk * 4 + 1] = y2;
            out[blk * 4 + 2] = wext;
            out[blk * 4 + 3] = hext;
        }
    }
}

extern "C" void kernel_launch(void* const* d_in, const int* in_sizes, int n_in,
                              void* d_out, int out_size, void* d_ws, size_t ws_size,
                              hipStream_t stream) {
    const float* x = (const float*)d_in[0];
    int* out = (int*)d_out;

    int* parent   = (int*)d_ws;                      // BB*HWSZ
    int* tileCnt  = parent + BB * HWSZ;              // NBLK
    int* tileList = tileCnt + NBLK;                  // NBLK*MAXR
    int* ids      = tileList + NBLK * MAXR;          // BB*KK
    int* dcol     = ids + BB * KK;                   // BB*KK*WW
    int* drow     = dcol + BB * KK * WW;             // BB*KK*HH (contiguous)

    void* args[] = { (void*)&x, (void*)&parent, (void*)&tileCnt, (void*)&tileList,
                     (void*)&ids, (void*)&dcol, (void*)&drow, (void*)&out };
    hipLaunchCooperativeKernel((const void*)fused_k, dim3(NBLK), dim3(256),
                               args, 0, stream);
}

// Round 9
// 94.562 us; speedup vs baseline: 2.2595x; 2.2595x over previous
//
#include <hip/hip_runtime.h>

#define BB 4
#define HH 384
#define WW 384
#define HWSZ (HH * WW)
#define KK 64

// --- CC tiling: 64x64, 512 threads, 144 blocks
#define CTS 64
#define CTPB 6                   // cc tiles per side
#define CNT (CTPB * CTPB)        // 36 per batch
#define CNBLK (BB * CNT)         // 144
#define CMAXR 2048

// --- accum tiling: 32x64, 256 threads, 288 blocks
#define ATSH 32
#define ATSW 64
#define ATPB_X 6
#define ANT 72                   // per batch

#define NS 8                     // root-cache slots per accum block
#define CANDC 2048
#define INFI 0x7FFFFFFF
#define INFV 0x7F7F7F7F
#define DTOT (BB * KK * (WW + HH))   // dcol+drow ints = 196608
#define DCHUNK 1366                  // ceil(DTOT / CNBLK)

// agent-scope (L1-bypass) load for data CAS-written in the same kernel
__device__ __forceinline__ int aload(const int* p) {
    return __hip_atomic_load(p, __ATOMIC_RELAXED, __HIP_MEMORY_SCOPE_AGENT);
}

__device__ __forceinline__ int afind(int* par, int i) {
    while (true) {
        int p = aload(&par[i]);
        if (p == i) return i;
        i = p;
    }
}

__device__ __forceinline__ void auni(int* par, int a, int b) {
    while (true) {
        a = afind(par, a);
        b = afind(par, b);
        if (a == b) return;
        if (a > b) { int t = a; a = b; b = t; }
        int old = atomicCAS(&par[b], b, a);
        if (old == b) return;
        b = old;
    }
}

// ---- union-find on LDS
__device__ __forceinline__ int lfind(int* par, int i) {
    while (true) {
        int p = par[i];
        if (p == i) return i;
        int gp = par[p];
        if (gp == p) return p;
        par[i] = gp;
        i = gp;
    }
}

__device__ __forceinline__ void luni(int* par, int a, int b) {
    while (true) {
        a = lfind(par, a);
        b = lfind(par, b);
        if (a == b) return;
        if (a > b) { int t = a; a = b; b = t; }
        int old = atomicCAS(&par[b], b, a);
        if (old == b) return;
        b = old;
    }
}

__device__ __forceinline__ int lookup_k(const int* sids, int r) {
    int lo = 0, hi = KK - 1;
    while (lo <= hi) {
        int mid = (lo + hi) >> 1;
        int v = sids[mid];
        if (v == r) return mid;
        if (v < r) lo = mid + 1; else hi = mid - 1;
    }
    return -1;
}

// 1. fused: dcol/drow init + mask + run-leader CC (64x64) + flatten + par write
__global__ __launch_bounds__(512) void cc_tile_k(const float* __restrict__ x,
                                                 int* __restrict__ parent,
                                                 int* __restrict__ tileCnt,
                                                 int* __restrict__ tileList,
                                                 int* __restrict__ dinit) {
    __shared__ int lp[CTS * CTS];               // 16 KB
    __shared__ unsigned short leadL[CMAXR];     // 4 KB
    __shared__ unsigned short rootL[CMAXR];     // 4 KB
    __shared__ int nLead, nRoot;
    int blk = blockIdx.x;
    int b = blk / CNT, t2 = blk - b * CNT;
    int th0 = (t2 / CTPB) * CTS, tw0 = (t2 % CTPB) * CTS;
    int* par = parent + b * HWSZ;
    int tid = threadIdx.x, ln = tid & 63, wv = tid >> 6;   // 8 waves

    {   // dcol/drow 0x7F init: this block's chunk
        int beg = blk * DCHUNK;
        int end = beg + DCHUNK; if (end > DTOT) end = DTOT;
        for (int i = beg + tid; i < end; i += 512) dinit[i] = INFV;
    }
    if (tid == 0) { nLead = 0; nRoot = 0; }
    __syncthreads();

    // pass 1: per-row horizontal run-leaders via ballot (wave == row)
    for (int r = wv; r < CTS; r += 8) {
        int h = th0 + r, w = tw0 + ln;
        int gi = (b * HH + h) * WW + w;
        float2 v = *(const float2*)(x + 2 * gi);
        bool m = (v.x > 0.4f) || (v.y > 0.4f);
        unsigned long long mb = __ballot(m);
        unsigned long long below = (~mb) & ((1ull << ln) - 1ull);
        int s = below ? (64 - __clzll(below)) : 0;
        int l = r * 64 + ln;
        lp[l] = m ? (r * 64 + s) : -1;
        if (m && s == ln) {
            int i2 = atomicAdd(&nLead, 1);
            leadL[i2] = (unsigned short)l;
        }
    }
    __syncthreads();
    // pass 2: vertical unions, one per overlap-run (dedup via ballot)
    for (int r = wv; r < CTS; r += 8) {
        if (r == 0) continue;                    // wave-uniform
        int l = r * 64 + ln;
        bool ov = (lp[l] >= 0) && (lp[l - 64] >= 0);
        unsigned long long ob = __ballot(ov);
        if (ov && (ln == 0 || !((ob >> (ln - 1)) & 1ull)))
            luni(lp, l, l - 64);
    }
    __syncthreads();
    // pass 2.5: flatten leaders exactly; collect roots
    int nl = nLead;
    for (int i = tid; i < nl; i += 512) {
        int l = leadL[i];
        int r = lfind(lp, l);
        if (r != l) lp[l] = r;                   // monotone, race-benign
        else { int j = atomicAdd(&nRoot, 1); rootL[j] = (unsigned short)l; }
    }
    __syncthreads();
    // pass 3: loop-free root per pixel (lp[l] -> leader, lp[leader] -> root)
    for (int l = tid; l < CTS * CTS; l += 512) {
        int v = lp[l];
        int h = th0 + (l >> 6), w = tw0 + (l & 63);
        int res = -1;
        if (v >= 0) {
            int r = lp[v];
            res = (th0 + (r >> 6)) * WW + (tw0 + (r & 63));
        }
        par[h * WW + w] = res;
    }
    int nr = nRoot;
    for (int i = tid; i < nr; i += 512) {
        int l = rootL[i];
        tileList[blk * CMAXR + i] = (th0 + (l >> 6)) * WW + (tw0 + (l & 63));
    }
    if (tid == 0) tileCnt[blk] = nr;
}

// 2. fused bridge + select, one block per batch.
//    Bridge edges lie on 64-aligned tile seams; mask fast-reject via plain
//    loads (sign stable), auni kept for general correctness.
__global__ __launch_bounds__(256) void selbr_k(const int* __restrict__ tileCnt,
                                               const int* __restrict__ tileList,
                                               int* __restrict__ parent,
                                               int* __restrict__ ids) {
    int b = blockIdx.x, tid = threadIdx.x;
    int* par = parent + b * HWSZ;

    // ---- bridge: 5 vertical + 5 horizontal seam lines, 3840 edges
    const int NEV = 5 * WW;
    const int NE = NEV + 5 * WW;
    for (int e = tid; e < NE; e += 256) {
        int p, q;
        if (e < NEV) {
            int line = e / WW, pos = e - line * WW;
            p = pos * WW + (63 + 64 * line); q = p + 1;
        } else {
            int eh = e - NEV;
            int line = eh / WW, pos = eh - line * WW;
            p = (63 + 64 * line) * WW + pos; q = p + WW;
        }
        if (par[p] >= 0 && par[q] >= 0) auni(par, p, q);
    }
    __syncthreads();

    // ---- select: KK smallest surviving roots, sorted
    __shared__ int pf[CNT + 1];
    __shared__ int cand[CANDC];
    __shared__ int cnt;
    if (tid < CNT) pf[tid + 1] = tileCnt[b * CNT + tid];
    if (tid == 0) { pf[0] = 0; cnt = 0; }
    if (tid < KK) ids[b * KK + tid] = INFI;
    __syncthreads();
    if (tid == 0) for (int i = 0; i < CNT; ++i) pf[i + 1] += pf[i];
    __syncthreads();
    int total = pf[CNT];
    for (int j = tid; j < total; j += 256) {
        int lo = 0, hi = CNT;
        while (lo + 1 < hi) { int mid = (lo + hi) >> 1; if (pf[mid] <= j) lo = mid; else hi = mid; }
        int v = tileList[(b * CNT + lo) * CMAXR + (j - pf[lo])];
        if (aload(&par[v]) == v) {               // L1-bypass after own-block CAS
            int pos = atomicAdd(&cnt, 1);
            if (pos < CANDC) cand[pos] = v;
        }
    }
    __syncthreads();
    int m2 = cnt < CANDC ? cnt : CANDC;
    for (int i = tid; i < m2; i += 256) {
        int v = cand[i];
        int r = 0;
        for (int j = 0; j < m2; ++j) r += (cand[j] < v);
        if (r < KK) ids[b * KK + r] = v;
    }
}

// 3. per 32x64 sub-tile: LDS-aggregated dilated col/row mins, memoized root, flush
__global__ __launch_bounds__(256) void accum_k(const int* __restrict__ parent,
                                               const int* __restrict__ ids,
                                               int* __restrict__ dcol,
                                               int* __restrict__ drow) {
    __shared__ int sids[KK];
    __shared__ unsigned long long table[NS];     // (root+1)<<32 | (k+2); 0 = empty
    __shared__ int scol[NS][ATSW];
    __shared__ int srow[NS][ATSH];
    int blk = blockIdx.x;
    int b = blk / ANT, t2 = blk - b * ANT;
    int th0 = (t2 / ATPB_X) * ATSH, tw0 = (t2 % ATPB_X) * ATSW;
    const int* par = parent + b * HWSZ;
    int tid = threadIdx.x;

    if (tid < KK) sids[tid] = ids[b * KK + tid];
    if (tid < NS) table[tid] = 0ull;
    for (int i = tid; i < NS * ATSW; i += 256) ((int*)scol)[i] = INFI;
    for (int i = tid; i < NS * ATSH; i += 256) ((int*)srow)[i] = INFI;
    __syncthreads();

    int lastpv = -2, lastk = -1, lastslot = -1;
    for (int c = 0; c < 2; ++c) {
        int base = (tid + c * 256) * 4;          // 0..2044
        int lh = base >> 6, lw = base & 63;
        int h = th0 + lh, w0 = tw0 + lw;
        int4 pr = *(const int4*)&par[h * WW + w0];
        int fh = (h >= 2) ? h - 2 : h;
        #pragma unroll
        for (int e = 0; e < 4; ++e) {
            int pv = (e == 0) ? pr.x : (e == 1) ? pr.y : (e == 2) ? pr.z : pr.w;
            if (pv < 0) continue;
            int k, slot;
            if (pv == lastpv) { k = lastk; slot = lastslot; }
            else {
                int r = pv, nx;
                while ((nx = aload(&par[r])) != r) r = nx;  // post-bridge chase
                k = -2; slot = -1;
                for (int i2 = 0; i2 < NS; ++i2) {
                    unsigned long long ev = table[i2];
                    if (ev == 0ull) {
                        if (k == -2) k = lookup_k(sids, r);
                        unsigned long long me =
                            ((unsigned long long)(unsigned)(r + 1) << 32) | (unsigned)(k + 2);
                        unsigned long long old = atomicCAS(&table[i2], 0ull, me);
                        if (old == 0ull) { slot = i2; break; }
                        ev = old;
                    }
                    if ((unsigned)(ev >> 32) == (unsigned)(r + 1)) {
                        k = (int)(unsigned)(ev & 0xffffffffull) - 2;
                        slot = i2; break;
                    }
                }
                if (slot < 0 && k == -2) k = lookup_k(sids, r);
                lastpv = pv; lastk = k; lastslot = slot;
            }
            if (k < 0) continue;
            int w = w0 + e;
            int fw = (w >= 2) ? w - 2 : w;
            if (slot >= 0) {
                atomicMin(&scol[slot][lw + e], fh);
                atomicMin(&srow[slot][lh], fw);
            } else {
                atomicMin(&dcol[(b * KK + k) * WW + w], fh);
                atomicMin(&drow[(b * KK + k) * HH + h], fw);
            }
        }
    }
    __syncthreads();
    for (int i = tid; i < NS * ATSW; i += 256) {
        int s = i >> 6, pos = i & 63;
        unsigned long long ev = table[s];
        if (ev == 0ull) continue;
        int k = (int)(unsigned)(ev & 0xffffffffull) - 2;
        if (k < 0) continue;
        int v = scol[s][pos];
        if (v < INFI) atomicMin(&dcol[(b * KK + k) * WW + tw0 + pos], v);
        if (pos < ATSH) {
            int v2 = srow[s][pos];
            if (v2 < INFI) atomicMin(&drow[(b * KK + k) * HH + th0 + pos], v2);
        }
    }
}

// 4. one block per (b,k): argmax!=0 semantics, reduce, emit bbox
__global__ __launch_bounds__(384) void bbox_k(const int* __restrict__ dcol,
                                              const int* __restrict__ drow,
                                              int* __restrict__ out) {
    int bk = blockIdx.x;
    int t = threadIdx.x;                         // 0..383 == WW == HH
    const int* dc = dcol + bk * WW;
    const int* dr = drow + bk * HH;

    int hm = dc[t];
    if (t >= 2) hm = min(hm, dc[t - 2]);
    if (t + 2 < WW) hm = min(hm, dc[t + 2]);
    bool mc = (hm < INFV) && (hm >= 1);
    int cmin = mc ? t : INFI;
    int cmax = mc ? t : -1;

    int wm = dr[t];
    if (t >= 2) wm = min(wm, dr[t - 2]);
    if (t + 2 < HH) wm = min(wm, dr[t + 2]);
    bool mr = (wm < INFV) && (wm >= 1);
    int rmin = mr ? t : INFI;
    int rmax = mr ? t : -1;

    for (int o = 1; o < 64; o <<= 1) {
        cmin = min(cmin, __shfl_xor(cmin, o));
        cmax = max(cmax, __shfl_xor(cmax, o));
        rmin = min(rmin, __shfl_xor(rmin, o));
        rmax = max(rmax, __shfl_xor(rmax, o));
    }
    __shared__ int s[4][6];
    int wv = t >> 6;
    if ((t & 63) == 0) { s[0][wv] = cmin; s[1][wv] = cmax; s[2][wv] = rmin; s[3][wv] = rmax; }
    __syncthreads();
    if (t == 0) {
        int CMin = s[0][0], CMax = s[1][0], RMin = s[2][0], RMax = s[3][0];
        for (int i = 1; i < 6; ++i) {
            CMin = min(CMin, s[0][i]); CMax = max(CMax, s[1][i]);
            RMin = min(RMin, s[2][i]); RMax = max(RMax, s[3][i]);
        }
        int x2, y2, wext, hext;
        if (RMax >= 0) { x2 = RMin; wext = RMax - RMin; } else { x2 = 0; wext = 1; }
        if (CMax >= 0) { y2 = CMin; hext = CMax - CMin; } else { y2 = 0; hext = 1; }
        out[bk * 4 + 0] = x2;
        out[bk * 4 + 1] = y2;
        out[bk * 4 + 2] = wext;
        out[bk * 4 + 3] = hext;
    }
}

extern "C" void kernel_launch(void* const* d_in, const int* in_sizes, int n_in,
                              void* d_out, int out_size, void* d_ws, size_t ws_size,
                              hipStream_t stream) {
    const float* x = (const float*)d_in[0];
    int* out = (int*)d_out;

    int* parent   = (int*)d_ws;                      // BB*HWSZ
    int* tileCnt  = parent + BB * HWSZ;              // CNBLK
    int* tileList = tileCnt + CNBLK;                 // CNBLK*CMAXR
    int* ids      = tileList + CNBLK * CMAXR;        // BB*KK
    int* dcol     = ids + BB * KK;                   // BB*KK*WW
    int* drow     = dcol + BB * KK * WW;             // BB*KK*HH (contiguous)

    cc_tile_k<<<CNBLK, 512, 0, stream>>>(x, parent, tileCnt, tileList, dcol);
    selbr_k<<<BB, 256, 0, stream>>>(tileCnt, tileList, parent, ids);
    accum_k<<<BB * ANT, 256, 0, stream>>>(parent, ids, dcol, drow);
    bbox_k<<<BB * KK, 384, 0, stream>>>(dcol, drow, out);
}